// Round 1
// baseline (442.385 us; speedup 1.0000x reference)
//
#include <hip/hip_runtime.h>
#include <hip/hip_bf16.h>

typedef unsigned short u16;
typedef __attribute__((ext_vector_type(8))) short bf16x8;
typedef __attribute__((ext_vector_type(4))) float f32x4;

#define DEV static __device__ __forceinline__

DEV u16 f2bf(float f) {
  union { float f; unsigned u; } v; v.f = f;
  unsigned r = v.u + 0x7fffu + ((v.u >> 16) & 1u);  // round-to-nearest-even
  return (u16)(r >> 16);
}

DEV void gll16(void* lds, const void* g) {
  __builtin_amdgcn_global_load_lds(
      (const __attribute__((address_space(1))) unsigned int*)g,
      (__attribute__((address_space(3))) unsigned int*)lds, 16, 0, 0);
}

// ---------------- pack: fp32 -> bf16 ----------------
__global__ __launch_bounds__(256) void cvt_f32_to_bf16(const float* __restrict__ in,
                                                       u16* __restrict__ out, int n4) {
  int i = blockIdx.x * blockDim.x + threadIdx.x;
  int stride = gridDim.x * blockDim.x;
  for (; i < n4; i += stride) {
    float4 f = ((const float4*)in)[i];
    ushort4 u;
    u.x = f2bf(f.x); u.y = f2bf(f.y); u.z = f2bf(f.z); u.w = f2bf(f.w);
    ((ushort4*)out)[i] = u;
  }
}

// ---------------- pack: W[K][N] fp32 -> Wt[N][K] bf16 ----------------
__global__ __launch_bounds__(256) void transpose_cvt(const float* __restrict__ W,
                                                     u16* __restrict__ Wt,
                                                     int K, int N) {
  __shared__ u16 t[64][65];
  const int k0 = blockIdx.x * 64, n0 = blockIdx.y * 64;
  const int tid = threadIdx.x;
  const int rr = tid >> 4;        // 0..15
  const int cc = (tid & 15) * 4;  // 0..60
#pragma unroll
  for (int i = 0; i < 4; ++i) {
    const int row = rr * 4 + i;
    float4 f = *(const float4*)&W[(size_t)(k0 + row) * N + n0 + cc];
    t[row][cc + 0] = f2bf(f.x);
    t[row][cc + 1] = f2bf(f.y);
    t[row][cc + 2] = f2bf(f.z);
    t[row][cc + 3] = f2bf(f.w);
  }
  __syncthreads();
#pragma unroll
  for (int i = 0; i < 4; ++i) {
    const int n = rr * 4 + i;
    ushort4 u;
    u.x = t[cc + 0][n]; u.y = t[cc + 1][n]; u.z = t[cc + 2][n]; u.w = t[cc + 3][n];
    *(ushort4*)&Wt[(size_t)(n0 + n) * K + k0 + cc] = u;
  }
}

// ---------------- bf16 GEMM: C[M][N] = A[M][K] * Bt[N][K]^T + bias ----------------
// 128x128 tile, BK=64, 256 threads (4 waves, 2x2), each wave 64x64 = 4x4 frags.
template<bool OUT_BF16>
__global__ __launch_bounds__(256) void gemm_bf16(const u16* __restrict__ A,
                                                 const u16* __restrict__ Bt,
                                                 const float* __restrict__ bias,
                                                 void* __restrict__ Cout,
                                                 int M, int N, int K) {
  __shared__ __align__(16) u16 As[128][64];
  __shared__ __align__(16) u16 Bs[128][64];
  const int tid = threadIdx.x;
  const int wave = tid >> 6, lane = tid & 63;
  const int g = lane >> 4, lr = lane & 15;
  const int bm = blockIdx.x * 128, bn = blockIdx.y * 128;
  const int wm = (wave >> 1) * 64, wn = (wave & 1) * 64;
  f32x4 acc[4][4] = {};
  for (int kt = 0; kt < K; kt += 64) {
    __syncthreads();
#pragma unroll
    for (int j = 0; j < 4; ++j) {
      int chunk = wave * 4 + j;          // 16 chunks of 1KB each per tile
      int e = chunk * 512 + lane * 8;    // element index in 128x64 tile
      int r = e >> 6, c = e & 63;
      gll16((u16*)As + chunk * 512, &A[(size_t)(bm + r) * K + kt + c]);
      gll16((u16*)Bs + chunk * 512, &Bt[(size_t)(bn + r) * K + kt + c]);
    }
    __syncthreads();
#pragma unroll
    for (int kk = 0; kk < 64; kk += 32) {
      bf16x8 af[4], bfr[4];
#pragma unroll
      for (int m = 0; m < 4; ++m)
        af[m] = *(const bf16x8*)&As[wm + m * 16 + lr][kk + g * 8];
#pragma unroll
      for (int n = 0; n < 4; ++n)
        bfr[n] = *(const bf16x8*)&Bs[wn + n * 16 + lr][kk + g * 8];
#pragma unroll
      for (int m = 0; m < 4; ++m)
#pragma unroll
        for (int n = 0; n < 4; ++n)
          acc[m][n] = __builtin_amdgcn_mfma_f32_16x16x32_bf16(af[m], bfr[n], acc[m][n], 0, 0, 0);
    }
  }
#pragma unroll
  for (int m = 0; m < 4; ++m) {
#pragma unroll
    for (int n = 0; n < 4; ++n) {
      const int col = bn + wn + n * 16 + lr;
      const float bv = bias ? bias[col] : 0.f;
#pragma unroll
      for (int r = 0; r < 4; ++r) {
        const int row = bm + wm + m * 16 + g * 4 + r;   // C/D: col=lane&15, row=(lane>>4)*4+reg
        float v = acc[m][n][r] + bv;
        if (OUT_BF16) ((u16*)Cout)[(size_t)row * N + col] = f2bf(v);
        else          ((float*)Cout)[(size_t)row * N + col] = v;
      }
    }
  }
}

// ---------------- flash attention ----------------
// grid (S/64, B*H); block 256 = 4 waves; wave w owns q rows [q0+16w, q0+16w+16).
// qkv: [B*S][3072] bf16 (q | k | v per head, d contiguous). out: [B*S][1024] bf16.
__global__ __launch_bounds__(256) void attn_kernel(const u16* __restrict__ qkv,
                                                   u16* __restrict__ out) {
  __shared__ __align__(16) u16 Ks[64][64];       // K tile [key][d]
  __shared__ __align__(16) u16 Vt[64][64];       // V tile transposed [d][key]
  __shared__ __align__(16) u16 Ps[4][16][64];    // per-wave P [qrow][key]
  const int tid = threadIdx.x;
  const int wave = tid >> 6, lane = tid & 63;
  const int g = lane >> 4, lr = lane & 15;
  const int b = blockIdx.y >> 4, h = blockIdx.y & 15;
  const int q0 = blockIdx.x * 64;
  const size_t base = (size_t)b * 2048 * 3072;
  const int qoff = h * 64, koff = 1024 + h * 64, voff = 2048 + h * 64;

  const int qrow = q0 + wave * 16 + lr;
  bf16x8 qf[2];
#pragma unroll
  for (int kk = 0; kk < 2; ++kk)
    qf[kk] = *(const bf16x8*)&qkv[base + (size_t)qrow * 3072 + qoff + kk * 32 + g * 8];

  f32x4 o[4] = {};
  float mrow[4] = {-1e30f, -1e30f, -1e30f, -1e30f};
  float lrow[4] = {0.f, 0.f, 0.f, 0.f};

  for (int t0 = 0; t0 < 2048; t0 += 64) {
    __syncthreads();
    // stage K tile (async, linear LDS)
#pragma unroll
    for (int j = 0; j < 2; ++j) {
      int chunk = wave * 2 + j;
      int e = chunk * 512 + lane * 8;
      int r = e >> 6, c = e & 63;
      gll16((u16*)Ks + chunk * 512, &qkv[base + (size_t)(t0 + r) * 3072 + koff + c]);
    }
    // stage V transposed via registers (coalesced global read, scatter LDS write)
#pragma unroll
    for (int j = 0; j < 2; ++j) {
      int cidx = tid + 256 * j;       // 0..511 chunks of 8
      int t = cidx & 63, dg = cidx >> 6;
      bf16x8 v = *(const bf16x8*)&qkv[base + (size_t)(t0 + t) * 3072 + voff + dg * 8];
#pragma unroll
      for (int i = 0; i < 8; ++i) Vt[dg * 8 + i][t] = (u16)v[i];
    }
    __syncthreads();

    // S = Q K^T  (D layout: col=key=lane&15 (+16n), row=qrow=(lane>>4)*4+reg)
    f32x4 s[4] = {};
#pragma unroll
    for (int kk = 0; kk < 2; ++kk) {
#pragma unroll
      for (int n = 0; n < 4; ++n) {
        bf16x8 kf = *(const bf16x8*)&Ks[n * 16 + lr][kk * 32 + g * 8];
        s[n] = __builtin_amdgcn_mfma_f32_16x16x32_bf16(qf[kk], kf, s[n], 0, 0, 0);
      }
    }
    // online softmax (rows live on 16-lane groups)
    float mnew[4], sc[4];
#pragma unroll
    for (int r = 0; r < 4; ++r) {
      float mx = fmaxf(fmaxf(s[0][r], s[1][r]), fmaxf(s[2][r], s[3][r]));
#pragma unroll
      for (int d = 1; d < 16; d <<= 1) mx = fmaxf(mx, __shfl_xor(mx, d));
      mnew[r] = fmaxf(mrow[r], 0.125f * mx);
      sc[r] = __expf(mrow[r] - mnew[r]);
      mrow[r] = mnew[r];
    }
#pragma unroll
    for (int r = 0; r < 4; ++r) {
      float sum = 0.f;
#pragma unroll
      for (int n = 0; n < 4; ++n) {
        float p = __expf(0.125f * s[n][r] - mnew[r]);
        sum += p;
        Ps[wave][g * 4 + r][n * 16 + lr] = f2bf(p);
      }
#pragma unroll
      for (int d = 1; d < 16; d <<= 1) sum += __shfl_xor(sum, d);
      lrow[r] = lrow[r] * sc[r] + sum;
    }
#pragma unroll
    for (int nd = 0; nd < 4; ++nd)
#pragma unroll
      for (int r = 0; r < 4; ++r) o[nd][r] *= sc[r];
    __syncthreads();   // P visible to all lanes; Vt staged
    // O += P V   (A=P from LDS, B=V via Vt, K-contiguous)
#pragma unroll
    for (int kk = 0; kk < 2; ++kk) {
      bf16x8 pf = *(const bf16x8*)&Ps[wave][lr][kk * 32 + g * 8];
#pragma unroll
      for (int nd = 0; nd < 4; ++nd) {
        bf16x8 vf = *(const bf16x8*)&Vt[nd * 16 + lr][kk * 32 + g * 8];
        o[nd] = __builtin_amdgcn_mfma_f32_16x16x32_bf16(pf, vf, o[nd], 0, 0, 0);
      }
    }
  }
  const size_t orow0 = (size_t)b * 2048 + q0 + wave * 16;
#pragma unroll
  for (int nd = 0; nd < 4; ++nd)
#pragma unroll
    for (int r = 0; r < 4; ++r) {
      float v = o[nd][r] / lrow[r];
      out[(orow0 + g * 4 + r) * 1024 + h * 64 + nd * 16 + lr] = f2bf(v);
    }
}

// ---------------- launcher ----------------
extern "C" void kernel_launch(void* const* d_in, const int* in_sizes, int n_in,
                              void* d_out, int out_size, void* d_ws, size_t ws_size,
                              hipStream_t stream) {
  (void)in_sizes; (void)n_in; (void)out_size; (void)ws_size;
  const float* x     = (const float*)d_in[0];  // [4,2048,1024]
  const float* w_in  = (const float*)d_in[1];  // [1024,3072]
  const float* b_in  = (const float*)d_in[2];  // [3072]
  const float* w_out = (const float*)d_in[3];  // [1024,1024]
  const float* b_out = (const float*)d_in[4];  // [1024]
  float* out = (float*)d_out;                  // [4,2048,1024] fp32

  char* ws = (char*)d_ws;
  u16* Xbf   = (u16*)ws; ws += (size_t)8192 * 1024 * 2;  // 16.8 MB
  u16* WinT  = (u16*)ws; ws += (size_t)3072 * 1024 * 2;  //  6.3 MB
  u16* WoutT = (u16*)ws; ws += (size_t)1024 * 1024 * 2;  //  2.1 MB
  u16* qkv   = (u16*)ws; ws += (size_t)8192 * 3072 * 2;  // 50.3 MB
  u16* attno = (u16*)ws; ws += (size_t)8192 * 1024 * 2;  // 16.8 MB   (total ~92.3 MB)

  cvt_f32_to_bf16<<<2048, 256, 0, stream>>>(x, Xbf, 8192 * 1024 / 4);
  transpose_cvt<<<dim3(16, 48), 256, 0, stream>>>(w_in, WinT, 1024, 3072);
  transpose_cvt<<<dim3(16, 16), 256, 0, stream>>>(w_out, WoutT, 1024, 1024);
  gemm_bf16<true ><<<dim3(64, 24), 256, 0, stream>>>(Xbf,   WinT,  b_in,  qkv, 8192, 3072, 1024);
  attn_kernel<<<dim3(32, 64), 256, 0, stream>>>(qkv, attno);
  gemm_bf16<false><<<dim3(64, 8),  256, 0, stream>>>(attno, WoutT, b_out, out, 8192, 1024, 1024);
}

// Round 2
// 345.883 us; speedup vs baseline: 1.2790x; 1.2790x over previous
//
#include <hip/hip_runtime.h>
#include <hip/hip_bf16.h>

typedef unsigned short u16;
typedef __attribute__((ext_vector_type(8))) short bf16x8;
typedef __attribute__((ext_vector_type(4))) float f32x4;

#define DEV static __device__ __forceinline__

DEV u16 f2bf(float f) {
  union { float f; unsigned u; } v; v.f = f;
  unsigned r = v.u + 0x7fffu + ((v.u >> 16) & 1u);  // round-to-nearest-even
  return (u16)(r >> 16);
}

DEV void gll16(void* lds, const void* g) {
  __builtin_amdgcn_global_load_lds(
      (const __attribute__((address_space(1))) unsigned int*)g,
      (__attribute__((address_space(3))) unsigned int*)lds, 16, 0, 0);
}

// Swizzled b128 read from a 64x64 u16 LDS tile (row stride 128B).
// Storage layout: logical (row, colbyte cb) lives at row*128 + (cb ^ ((row&7)<<4)).
DEV bf16x8 lds_swz_read(const u16* tile, int row, int colbyte) {
  const char* p = (const char*)tile + row * 128 + (colbyte ^ ((row & 7) << 4));
  return *(const bf16x8*)p;
}

// Stage a 64x64 u16 tile into swizzled LDS layout via global_load_lds:
// linear LDS dest (HW: base + lane*16), inverse-swizzled global source (rule #21).
DEV void stage_swz(u16* lds_tile, const u16* gbase, int gstride, int wave, int lane) {
#pragma unroll
  for (int j = 0; j < 2; ++j) {
    const int chunk = wave * 2 + j;          // 8 chunks x 1KB
    const int a = chunk * 1024 + lane * 16;  // linear LDS byte this lane writes
    const int r = a >> 7;                    // tile row
    const int cb = (a & 127) ^ ((r & 7) << 4);  // logical colbyte stored here
    gll16(lds_tile + chunk * 512, &gbase[(size_t)r * gstride + (cb >> 1)]);
  }
}

// ---------------- pack: fp32 -> bf16 ----------------
__global__ __launch_bounds__(256) void cvt_f32_to_bf16(const float* __restrict__ in,
                                                       u16* __restrict__ out, int n4) {
  int i = blockIdx.x * blockDim.x + threadIdx.x;
  int stride = gridDim.x * blockDim.x;
  for (; i < n4; i += stride) {
    float4 f = ((const float4*)in)[i];
    ushort4 u;
    u.x = f2bf(f.x); u.y = f2bf(f.y); u.z = f2bf(f.z); u.w = f2bf(f.w);
    ((ushort4*)out)[i] = u;
  }
}

// ---------------- pack: W[K][N] fp32 -> Wt[N][K] bf16, cols < sn scaled ----------------
__global__ __launch_bounds__(256) void transpose_cvt(const float* __restrict__ W,
                                                     u16* __restrict__ Wt,
                                                     int K, int N, int sn, float sval) {
  __shared__ u16 t[64][65];
  const int k0 = blockIdx.x * 64, n0 = blockIdx.y * 64;
  const int tid = threadIdx.x;
  const int rr = tid >> 4;        // 0..15
  const int cc = (tid & 15) * 4;  // 0..60
  const float scl = (n0 < sn) ? sval : 1.0f;   // n0 is 64-aligned, sn is 1024
#pragma unroll
  for (int i = 0; i < 4; ++i) {
    const int row = rr * 4 + i;
    float4 f = *(const float4*)&W[(size_t)(k0 + row) * N + n0 + cc];
    t[row][cc + 0] = f2bf(f.x * scl);
    t[row][cc + 1] = f2bf(f.y * scl);
    t[row][cc + 2] = f2bf(f.z * scl);
    t[row][cc + 3] = f2bf(f.w * scl);
  }
  __syncthreads();
#pragma unroll
  for (int i = 0; i < 4; ++i) {
    const int n = rr * 4 + i;
    ushort4 u;
    u.x = t[cc + 0][n]; u.y = t[cc + 1][n]; u.z = t[cc + 2][n]; u.w = t[cc + 3][n];
    *(ushort4*)&Wt[(size_t)(n0 + n) * K + k0 + cc] = u;
  }
}

// ---------------- transpose V part of qkv: -> vT[bh][d][t] ----------------
__global__ __launch_bounds__(256) void transpose_v(const u16* __restrict__ qkv,
                                                   u16* __restrict__ vT) {
  __shared__ u16 t[64][72];
  const int bh = blockIdx.y;          // b*16+h
  const int b = bh >> 4, h = bh & 15;
  const int t0 = blockIdx.x * 64;
  const int tid = threadIdx.x;
  const int row = tid >> 2;           // token within tile, 0..63
  const int cg = (tid & 3) * 16;      // d group
  const size_t src = (size_t)b * 2048 * 3072 + (size_t)(t0 + row) * 3072 + 2048 + h * 64 + cg;
  bf16x8 v0 = *(const bf16x8*)&qkv[src];
  bf16x8 v1 = *(const bf16x8*)&qkv[src + 8];
#pragma unroll
  for (int i = 0; i < 8; ++i) { t[row][cg + i] = (u16)v0[i]; t[row][cg + 8 + i] = (u16)v1[i]; }
  __syncthreads();
  const int d = tid >> 2;             // 0..63
  const int tg = (tid & 3) * 16;
  bf16x8 o0, o1;
#pragma unroll
  for (int i = 0; i < 8; ++i) { o0[i] = (short)t[tg + i][d]; o1[i] = (short)t[tg + 8 + i][d]; }
  u16* dst = &vT[((size_t)bh * 64 + d) * 2048 + t0 + tg];
  *(bf16x8*)dst = o0;
  *(bf16x8*)(dst + 8) = o1;
}

// ---------------- bf16 GEMM: C[M][N] = A[M][K] * Bt[N][K]^T + bias ----------------
// 128x128 tile, BK=64, 256 threads (4 waves, 2x2), each wave 64x64 = 4x4 frags.
// Bias for cols < qn is scaled by 0.125 (Q pre-scale; W already scaled in pack).
template<bool OUT_BF16>
__global__ __launch_bounds__(256) void gemm_bf16(const u16* __restrict__ A,
                                                 const u16* __restrict__ Bt,
                                                 const float* __restrict__ bias,
                                                 void* __restrict__ Cout,
                                                 int M, int N, int K, int qn) {
  __shared__ __align__(16) u16 As[128][64];
  __shared__ __align__(16) u16 Bs[128][64];
  const int tid = threadIdx.x;
  const int wave = tid >> 6, lane = tid & 63;
  const int g = lane >> 4, lr = lane & 15;
  const int bm = blockIdx.x * 128, bn = blockIdx.y * 128;
  const int wm = (wave >> 1) * 64, wn = (wave & 1) * 64;
  f32x4 acc[4][4] = {};
  for (int kt = 0; kt < K; kt += 64) {
    __syncthreads();
#pragma unroll
    for (int j = 0; j < 4; ++j) {
      int chunk = wave * 4 + j;          // 16 chunks of 1KB each per tile
      int e = chunk * 512 + lane * 8;    // element index in 128x64 tile
      int r = e >> 6, c = e & 63;
      gll16((u16*)As + chunk * 512, &A[(size_t)(bm + r) * K + kt + c]);
      gll16((u16*)Bs + chunk * 512, &Bt[(size_t)(bn + r) * K + kt + c]);
    }
    __syncthreads();
#pragma unroll
    for (int kk = 0; kk < 64; kk += 32) {
      bf16x8 af[4], bfr[4];
#pragma unroll
      for (int m = 0; m < 4; ++m)
        af[m] = *(const bf16x8*)&As[wm + m * 16 + lr][kk + g * 8];
#pragma unroll
      for (int n = 0; n < 4; ++n)
        bfr[n] = *(const bf16x8*)&Bs[wn + n * 16 + lr][kk + g * 8];
#pragma unroll
      for (int m = 0; m < 4; ++m)
#pragma unroll
        for (int n = 0; n < 4; ++n)
          acc[m][n] = __builtin_amdgcn_mfma_f32_16x16x32_bf16(af[m], bfr[n], acc[m][n], 0, 0, 0);
    }
  }
#pragma unroll
  for (int m = 0; m < 4; ++m) {
#pragma unroll
    for (int n = 0; n < 4; ++n) {
      const int col = bn + wn + n * 16 + lr;
      float bv = bias ? bias[col] : 0.f;
      if (col < qn) bv *= 0.125f;
#pragma unroll
      for (int r = 0; r < 4; ++r) {
        const int row = bm + wm + m * 16 + g * 4 + r;   // C/D: col=lane&15, row=(lane>>4)*4+reg
        float v = acc[m][n][r] + bv;
        if (OUT_BF16) ((u16*)Cout)[(size_t)row * N + col] = f2bf(v);
        else          ((float*)Cout)[(size_t)row * N + col] = v;
      }
    }
  }
}

// ---------------- flash attention (swizzled LDS, 2-phase double-buffer) ----------------
// grid (S/64, B*H); block 256 = 4 waves; wave w owns q rows [q0+16w, q0+16w+16).
// qkv: [B*S][3072] bf16 (Q pre-scaled by 0.125); vT: [bh][d][t]. out: [B*S][1024] bf16.
__global__ __launch_bounds__(256) void attn_kernel(const u16* __restrict__ qkv,
                                                   const u16* __restrict__ vT,
                                                   u16* __restrict__ out) {
  __shared__ __align__(16) u16 Ks[2][4096];   // K tile [key][d], swizzled
  __shared__ __align__(16) u16 Vs[2][4096];   // V^T tile [d][key], swizzled
  __shared__ __align__(16) u16 Ps[4][1024];   // per-wave P [qrow][key], swizzled
  const int tid = threadIdx.x;
  const int wave = tid >> 6, lane = tid & 63;
  const int g = lane >> 4, lr = lane & 15;
  const int bh = blockIdx.y;
  const int b = bh >> 4, h = bh & 15;
  const int q0 = blockIdx.x * 64;
  const size_t base = (size_t)b * 2048 * 3072;
  const u16* kg = qkv + base + 1024 + h * 64;        // + t*3072 + d
  const u16* vg = vT + (size_t)bh * 64 * 2048;       // + d*2048 + t

  const int qrow = q0 + wave * 16 + lr;
  bf16x8 qf[2];
#pragma unroll
  for (int kk = 0; kk < 2; ++kk)
    qf[kk] = *(const bf16x8*)&qkv[base + (size_t)qrow * 3072 + h * 64 + kk * 32 + g * 8];

  f32x4 o[4] = {};
  float mrow[4] = {-1e30f, -1e30f, -1e30f, -1e30f};
  float lrow[4] = {0.f, 0.f, 0.f, 0.f};

  stage_swz(Ks[0], kg, 3072, wave, lane);
  stage_swz(Vs[0], vg, 2048, wave, lane);
  __syncthreads();
  int cur = 0;
  for (int it = 0; it < 32; ++it) {
    // issue next-tile stage before compute (2-phase; barrier at loop end drains vmcnt)
    if (it < 31) {
      stage_swz(Ks[cur ^ 1], kg + (size_t)(it + 1) * 64 * 3072, 3072, wave, lane);
      stage_swz(Vs[cur ^ 1], vg + (it + 1) * 64, 2048, wave, lane);
    }
    // S = Q K^T  (D layout: col=key=lr(+16n), row=qrow=g*4+reg)
    f32x4 s[4] = {};
#pragma unroll
    for (int kk = 0; kk < 2; ++kk)
#pragma unroll
      for (int n = 0; n < 4; ++n) {
        bf16x8 kf = lds_swz_read(Ks[cur], n * 16 + lr, kk * 64 + g * 16);
        s[n] = __builtin_amdgcn_mfma_f32_16x16x32_bf16(qf[kk], kf, s[n], 0, 0, 0);
      }
    // online softmax (rows live on 16-lane groups); scale already folded into Q
    float mnew[4], sc[4];
#pragma unroll
    for (int r = 0; r < 4; ++r) {
      float mx = fmaxf(fmaxf(s[0][r], s[1][r]), fmaxf(s[2][r], s[3][r]));
#pragma unroll
      for (int d = 1; d < 16; d <<= 1) mx = fmaxf(mx, __shfl_xor(mx, d));
      mnew[r] = fmaxf(mrow[r], mx);
      sc[r] = __expf(mrow[r] - mnew[r]);
      mrow[r] = mnew[r];
    }
    char* pw = (char*)Ps[wave];
#pragma unroll
    for (int r = 0; r < 4; ++r) {
      const int prow = g * 4 + r;
      char* rowp = pw + prow * 128;
      const int sw = (prow & 7) << 4;
      float sum = 0.f;
#pragma unroll
      for (int n = 0; n < 4; ++n) {
        float p = __expf(s[n][r] - mnew[r]);
        sum += p;
        *(u16*)(rowp + (((n * 16 + lr) * 2) ^ sw)) = f2bf(p);
      }
#pragma unroll
      for (int d = 1; d < 16; d <<= 1) sum += __shfl_xor(sum, d);
      lrow[r] = lrow[r] * sc[r] + sum;
    }
#pragma unroll
    for (int nd = 0; nd < 4; ++nd)
#pragma unroll
      for (int r = 0; r < 4; ++r) o[nd][r] *= sc[r];
    // O += P V   (A=P from per-wave LDS, B=V^T tile; intra-wave lgkmcnt orders Ps)
#pragma unroll
    for (int kk = 0; kk < 2; ++kk) {
      bf16x8 pf = lds_swz_read(Ps[wave], lr, kk * 64 + g * 16);
#pragma unroll
      for (int nd = 0; nd < 4; ++nd) {
        bf16x8 vf = lds_swz_read(Vs[cur], nd * 16 + lr, kk * 64 + g * 16);
        o[nd] = __builtin_amdgcn_mfma_f32_16x16x32_bf16(pf, vf, o[nd], 0, 0, 0);
      }
    }
    __syncthreads();
    cur ^= 1;
  }
  const size_t orow0 = (size_t)b * 2048 + q0 + wave * 16;
#pragma unroll
  for (int nd = 0; nd < 4; ++nd)
#pragma unroll
    for (int r = 0; r < 4; ++r) {
      float v = o[nd][r] / lrow[r];
      out[(orow0 + g * 4 + r) * 1024 + h * 64 + nd * 16 + lr] = f2bf(v);
    }
}

// ---------------- launcher ----------------
extern "C" void kernel_launch(void* const* d_in, const int* in_sizes, int n_in,
                              void* d_out, int out_size, void* d_ws, size_t ws_size,
                              hipStream_t stream) {
  (void)in_sizes; (void)n_in; (void)out_size; (void)ws_size;
  const float* x     = (const float*)d_in[0];  // [4,2048,1024]
  const float* w_in  = (const float*)d_in[1];  // [1024,3072]
  const float* b_in  = (const float*)d_in[2];  // [3072]
  const float* w_out = (const float*)d_in[3];  // [1024,1024]
  const float* b_out = (const float*)d_in[4];  // [1024]
  float* out = (float*)d_out;                  // [4,2048,1024] fp32

  char* ws = (char*)d_ws;
  u16* Xbf   = (u16*)ws; ws += (size_t)8192 * 1024 * 2;  // 16.8 MB (reused as vT after gemm1)
  u16* WinT  = (u16*)ws; ws += (size_t)3072 * 1024 * 2;  //  6.3 MB
  u16* WoutT = (u16*)ws; ws += (size_t)1024 * 1024 * 2;  //  2.1 MB
  u16* qkv   = (u16*)ws; ws += (size_t)8192 * 3072 * 2;  // 50.3 MB
  u16* attno = (u16*)ws; ws += (size_t)8192 * 1024 * 2;  // 16.8 MB   (total ~92.3 MB)
  u16* vT    = Xbf;  // alias: Xbf dead after gemm1; vT written after gemm1 (stream-ordered)

  cvt_f32_to_bf16<<<2048, 256, 0, stream>>>(x, Xbf, 8192 * 1024 / 4);
  transpose_cvt<<<dim3(16, 48), 256, 0, stream>>>(w_in, WinT, 1024, 3072, 1024, 0.125f);
  transpose_cvt<<<dim3(16, 16), 256, 0, stream>>>(w_out, WoutT, 1024, 1024, 0, 1.0f);
  gemm_bf16<true ><<<dim3(64, 24), 256, 0, stream>>>(Xbf,   WinT,  b_in,  qkv, 8192, 3072, 1024, 1024);
  transpose_v<<<dim3(32, 64), 256, 0, stream>>>(qkv, vT);
  attn_kernel<<<dim3(32, 64), 256, 0, stream>>>(qkv, vT, attno);
  gemm_bf16<false><<<dim3(64, 8),  256, 0, stream>>>(attno, WoutT, b_out, out, 8192, 1024, 1024, 0);
}

// Round 3
// 264.982 us; speedup vs baseline: 1.6695x; 1.3053x over previous
//
#include <hip/hip_runtime.h>
#include <hip/hip_bf16.h>

typedef unsigned short u16;
typedef __attribute__((ext_vector_type(8))) short bf16x8;
typedef __attribute__((ext_vector_type(4))) float f32x4;

#define QSCALE 0.180336880f   // 0.125 * log2(e): softmax computed in exp2 domain

#define DEV static __device__ __forceinline__

DEV u16 f2bf(float f) {
  union { float f; unsigned u; } v; v.f = f;
  unsigned r = v.u + 0x7fffu + ((v.u >> 16) & 1u);  // round-to-nearest-even
  return (u16)(r >> 16);
}

DEV unsigned pk2(float a, float b) {   // two f32 -> packed bf16x2 (RNE)
  union { __hip_bfloat162 h; unsigned u; } c;
  c.h = __float22bfloat162_rn(make_float2(a, b));
  return c.u;
}

DEV void gll16(void* lds, const void* g) {
  __builtin_amdgcn_global_load_lds(
      (const __attribute__((address_space(1))) unsigned int*)g,
      (__attribute__((address_space(3))) unsigned int*)lds, 16, 0, 0);
}

// Swizzled b128 read from a 64x64 u16 LDS tile (row stride 128B).
// Storage layout: logical (row, colbyte cb) lives at row*128 + (cb ^ ((row&7)<<4)).
DEV bf16x8 lds_swz_read(const u16* tile, int row, int colbyte) {
  const char* p = (const char*)tile + row * 128 + (colbyte ^ ((row & 7) << 4));
  return *(const bf16x8*)p;
}

// Stage a 64x64 u16 tile into swizzled LDS layout via global_load_lds:
// linear LDS dest (HW: base + lane*16), inverse-swizzled global source (rule #21).
DEV void stage_swz(u16* lds_tile, const u16* gbase, int gstride, int wave, int lane) {
#pragma unroll
  for (int j = 0; j < 2; ++j) {
    const int chunk = wave * 2 + j;          // 8 chunks x 1KB
    const int a = chunk * 1024 + lane * 16;  // linear LDS byte this lane writes
    const int r = a >> 7;                    // tile row
    const int cb = (a & 127) ^ ((r & 7) << 4);  // logical colbyte stored here
    gll16(lds_tile + chunk * 512, &gbase[(size_t)r * gstride + (cb >> 1)]);
  }
}

// ---------------- pack: fp32 -> bf16 ----------------
__global__ __launch_bounds__(256) void cvt_f32_to_bf16(const float* __restrict__ in,
                                                       u16* __restrict__ out, int n4) {
  int i = blockIdx.x * blockDim.x + threadIdx.x;
  int stride = gridDim.x * blockDim.x;
  for (; i < n4; i += stride) {
    float4 f = ((const float4*)in)[i];
    ushort4 u;
    u.x = f2bf(f.x); u.y = f2bf(f.y); u.z = f2bf(f.z); u.w = f2bf(f.w);
    ((ushort4*)out)[i] = u;
  }
}

// ---------------- pack: W[K][N] fp32 -> Wt[N][K] bf16, cols < sn scaled ----------------
__global__ __launch_bounds__(256) void transpose_cvt(const float* __restrict__ W,
                                                     u16* __restrict__ Wt,
                                                     int K, int N, int sn, float sval) {
  __shared__ u16 t[64][65];
  const int k0 = blockIdx.x * 64, n0 = blockIdx.y * 64;
  const int tid = threadIdx.x;
  const int rr = tid >> 4;        // 0..15
  const int cc = (tid & 15) * 4;  // 0..60
  const float scl = (n0 < sn) ? sval : 1.0f;   // n0 is 64-aligned, sn is 1024
#pragma unroll
  for (int i = 0; i < 4; ++i) {
    const int row = rr * 4 + i;
    float4 f = *(const float4*)&W[(size_t)(k0 + row) * N + n0 + cc];
    t[row][cc + 0] = f2bf(f.x * scl);
    t[row][cc + 1] = f2bf(f.y * scl);
    t[row][cc + 2] = f2bf(f.z * scl);
    t[row][cc + 3] = f2bf(f.w * scl);
  }
  __syncthreads();
#pragma unroll
  for (int i = 0; i < 4; ++i) {
    const int n = rr * 4 + i;
    ushort4 u;
    u.x = t[cc + 0][n]; u.y = t[cc + 1][n]; u.z = t[cc + 2][n]; u.w = t[cc + 3][n];
    *(ushort4*)&Wt[(size_t)(n0 + n) * K + k0 + cc] = u;
  }
}

// ---------------- transpose V part of qkv: -> vT[bh][d][t] ----------------
__global__ __launch_bounds__(256) void transpose_v(const u16* __restrict__ qkv,
                                                   u16* __restrict__ vT) {
  __shared__ u16 t[64][72];
  const int bh = blockIdx.y;          // b*16+h
  const int b = bh >> 4, h = bh & 15;
  const int t0 = blockIdx.x * 64;
  const int tid = threadIdx.x;
  const int row = tid >> 2;           // token within tile, 0..63
  const int cg = (tid & 3) * 16;      // d group
  const size_t src = (size_t)b * 2048 * 3072 + (size_t)(t0 + row) * 3072 + 2048 + h * 64 + cg;
  bf16x8 v0 = *(const bf16x8*)&qkv[src];
  bf16x8 v1 = *(const bf16x8*)&qkv[src + 8];
#pragma unroll
  for (int i = 0; i < 8; ++i) { t[row][cg + i] = (u16)v0[i]; t[row][cg + 8 + i] = (u16)v1[i]; }
  __syncthreads();
  const int d = tid >> 2;             // 0..63
  const int tg = (tid & 3) * 16;
  bf16x8 o0, o1;
#pragma unroll
  for (int i = 0; i < 8; ++i) { o0[i] = (short)t[tg + i][d]; o1[i] = (short)t[tg + 8 + i][d]; }
  u16* dst = &vT[((size_t)bh * 64 + d) * 2048 + t0 + tg];
  *(bf16x8*)dst = o0;
  *(bf16x8*)(dst + 8) = o1;
}

// ---------------- bf16 GEMM: C[M][N] = A[M][K] * Bt[N][K]^T + bias ----------------
// 128x128 tile, BK=64, 256 threads (4 waves, 2x2), each wave 64x64 = 4x4 frags.
// Bias for cols < qn is scaled by QSCALE (Q pre-scale; W already scaled in pack).
template<bool OUT_BF16>
__global__ __launch_bounds__(256) void gemm_bf16(const u16* __restrict__ A,
                                                 const u16* __restrict__ Bt,
                                                 const float* __restrict__ bias,
                                                 void* __restrict__ Cout,
                                                 int M, int N, int K, int qn) {
  __shared__ __align__(16) u16 As[128][64];
  __shared__ __align__(16) u16 Bs[128][64];
  const int tid = threadIdx.x;
  const int wave = tid >> 6, lane = tid & 63;
  const int g = lane >> 4, lr = lane & 15;
  const int bm = blockIdx.x * 128, bn = blockIdx.y * 128;
  const int wm = (wave >> 1) * 64, wn = (wave & 1) * 64;
  f32x4 acc[4][4] = {};
  for (int kt = 0; kt < K; kt += 64) {
    __syncthreads();
#pragma unroll
    for (int j = 0; j < 4; ++j) {
      int chunk = wave * 4 + j;          // 16 chunks of 1KB each per tile
      int e = chunk * 512 + lane * 8;    // element index in 128x64 tile
      int r = e >> 6, c = e & 63;
      gll16((u16*)As + chunk * 512, &A[(size_t)(bm + r) * K + kt + c]);
      gll16((u16*)Bs + chunk * 512, &Bt[(size_t)(bn + r) * K + kt + c]);
    }
    __syncthreads();
#pragma unroll
    for (int kk = 0; kk < 64; kk += 32) {
      bf16x8 af[4], bfr[4];
#pragma unroll
      for (int m = 0; m < 4; ++m)
        af[m] = *(const bf16x8*)&As[wm + m * 16 + lr][kk + g * 8];
#pragma unroll
      for (int n = 0; n < 4; ++n)
        bfr[n] = *(const bf16x8*)&Bs[wn + n * 16 + lr][kk + g * 8];
#pragma unroll
      for (int m = 0; m < 4; ++m)
#pragma unroll
        for (int n = 0; n < 4; ++n)
          acc[m][n] = __builtin_amdgcn_mfma_f32_16x16x32_bf16(af[m], bfr[n], acc[m][n], 0, 0, 0);
    }
  }
#pragma unroll
  for (int m = 0; m < 4; ++m) {
#pragma unroll
    for (int n = 0; n < 4; ++n) {
      const int col = bn + wn + n * 16 + lr;
      float bv = bias ? bias[col] : 0.f;
      if (col < qn) bv *= QSCALE;
#pragma unroll
      for (int r = 0; r < 4; ++r) {
        const int row = bm + wm + m * 16 + g * 4 + r;   // C/D: col=lane&15, row=(lane>>4)*4+reg
        float v = acc[m][n][r] + bv;
        if (OUT_BF16) ((u16*)Cout)[(size_t)row * N + col] = f2bf(v);
        else          ((float*)Cout)[(size_t)row * N + col] = v;
      }
    }
  }
}

// ---------------- flash attention: swapped QK^T, in-register softmax, defer-max ----
// grid (S/64, B*H); block 256 = 4 waves; wave w owns q rows [q0+16w, q0+16w+16).
// qkv: [B*S][3072] bf16 (Q pre-scaled by QSCALE = 0.125*log2e); vT: [bh][d][t].
// Swapped QK: s[n] = mfma(kf, qf) -> s[n][r] = S[key=n*16+g*4+r][q=lr] (lane owns row lr).
__global__ __launch_bounds__(256) void attn_kernel(const u16* __restrict__ qkv,
                                                   const u16* __restrict__ vT,
                                                   u16* __restrict__ out) {
  __shared__ __align__(16) u16 Ks[2][4096];   // K tile [key][d], swizzled
  __shared__ __align__(16) u16 Vs[2][4096];   // V^T tile [d][key], swizzled
  __shared__ __align__(16) u16 Ps[4][1024];   // per-wave P [qrow][key], swizzled
  const int tid = threadIdx.x;
  const int wave = tid >> 6, lane = tid & 63;
  const int g = lane >> 4, lr = lane & 15;
  const int bh = blockIdx.y;
  const int b = bh >> 4, h = bh & 15;
  const int q0 = blockIdx.x * 64;
  const size_t base = (size_t)b * 2048 * 3072;
  const u16* kg = qkv + base + 1024 + h * 64;        // + t*3072 + d
  const u16* vg = vT + (size_t)bh * 64 * 2048;       // + d*2048 + t

  const int qrow = q0 + wave * 16 + lr;
  bf16x8 qf[2];
#pragma unroll
  for (int kk = 0; kk < 2; ++kk)
    qf[kk] = *(const bf16x8*)&qkv[base + (size_t)qrow * 3072 + h * 64 + kk * 32 + g * 8];

  f32x4 o[4] = {};
  float m = -1e30f, lsum = 0.f;

  stage_swz(Ks[0], kg, 3072, wave, lane);
  stage_swz(Vs[0], vg, 2048, wave, lane);
  __syncthreads();
  int cur = 0;
  char* const pwrow = (char*)Ps[wave] + lr * 128;   // this lane's q-row in P tile
  const int psw = (lr & 7) << 4;
  for (int it = 0; it < 32; ++it) {
    if (it < 31) {
      stage_swz(Ks[cur ^ 1], kg + (size_t)(it + 1) * 64 * 3072, 3072, wave, lane);
      stage_swz(Vs[cur ^ 1], vg + (it + 1) * 64, 2048, wave, lane);
    }
    // S^T = K Q^T (same fragments as QK, swapped operands)
    f32x4 s[4] = {};
#pragma unroll
    for (int kk = 0; kk < 2; ++kk)
#pragma unroll
      for (int n = 0; n < 4; ++n) {
        bf16x8 kf = lds_swz_read(Ks[cur], n * 16 + lr, kk * 64 + g * 16);
        s[n] = __builtin_amdgcn_mfma_f32_16x16x32_bf16(kf, qf[kk], s[n], 0, 0, 0);
      }
    // per-lane max over the 16 held scores (all for q-row lr)
    f32x4 t01, t23;
#pragma unroll
    for (int i = 0; i < 4; ++i) {
      t01[i] = fmaxf(s[0][i], s[1][i]);
      t23[i] = fmaxf(s[2][i], s[3][i]);
    }
    f32x4 t = { fmaxf(t01[0], t23[0]), fmaxf(t01[1], t23[1]),
                fmaxf(t01[2], t23[2]), fmaxf(t01[3], t23[3]) };
    float pmax = fmaxf(fmaxf(t[0], t[1]), fmaxf(t[2], t[3]));
    // defer-max (T13): rescale only when some row's max grew past m+8 (log2 domain)
    if (!__all(pmax <= m + 8.f)) {
      float pm = fmaxf(pmax, __shfl_xor(pmax, 16));
      pm = fmaxf(pm, __shfl_xor(pm, 32));
      float mnew = fmaxf(m, pm);
      float sc = __builtin_amdgcn_exp2f(m - mnew);
      // o rows are g*4+r; fetch their scales from lanes lr'=g*4+r
      float sc0 = __shfl(sc, g * 4 + 0);
      float sc1 = __shfl(sc, g * 4 + 1);
      float sc2 = __shfl(sc, g * 4 + 2);
      float sc3 = __shfl(sc, g * 4 + 3);
#pragma unroll
      for (int nd = 0; nd < 4; ++nd) {
        o[nd][0] *= sc0; o[nd][1] *= sc1; o[nd][2] *= sc2; o[nd][3] *= sc3;
      }
      lsum *= sc;
      m = mnew;
    }
    // p = exp2(s - m) (bounded by 2^8); pack pairs; one b64 write per n
    float su = 0.f;
#pragma unroll
    for (int n = 0; n < 4; ++n) {
      float p0 = __builtin_amdgcn_exp2f(s[n][0] - m);
      float p1 = __builtin_amdgcn_exp2f(s[n][1] - m);
      float p2 = __builtin_amdgcn_exp2f(s[n][2] - m);
      float p3 = __builtin_amdgcn_exp2f(s[n][3] - m);
      uint2 w;
      w.x = pk2(p0, p1);
      w.y = pk2(p2, p3);
      *(uint2*)(pwrow + ((n * 32 + g * 8) ^ psw)) = w;   // keys n*16+g*4+0..3, row lr
      su += (p0 + p1) + (p2 + p3);
    }
    lsum += su;   // per-lane partial (this lane's 16 keys of row lr); reduced at end
    // O += P V  (A = P rows=q, k=key; B = V^T rows=d, k=key)
#pragma unroll
    for (int kk = 0; kk < 2; ++kk) {
      bf16x8 pf = lds_swz_read(Ps[wave], lr, kk * 64 + g * 16);
#pragma unroll
      for (int nd = 0; nd < 4; ++nd) {
        bf16x8 vf = lds_swz_read(Vs[cur], nd * 16 + lr, kk * 64 + g * 16);
        o[nd] = __builtin_amdgcn_mfma_f32_16x16x32_bf16(pf, vf, o[nd], 0, 0, 0);
      }
    }
    __syncthreads();
    cur ^= 1;
  }
  // final row-sum reduce + redistribute to o's rows (g*4+r)
  float lf = lsum + __shfl_xor(lsum, 16);
  lf += __shfl_xor(lf, 32);
  float l0 = __shfl(lf, g * 4 + 0);
  float l1 = __shfl(lf, g * 4 + 1);
  float l2 = __shfl(lf, g * 4 + 2);
  float l3 = __shfl(lf, g * 4 + 3);
  const size_t orow0 = (size_t)b * 2048 + q0 + wave * 16;
#pragma unroll
  for (int nd = 0; nd < 4; ++nd) {
    const int dcol = h * 64 + nd * 16 + lr;
    out[(orow0 + g * 4 + 0) * 1024 + dcol] = f2bf(o[nd][0] / l0);
    out[(orow0 + g * 4 + 1) * 1024 + dcol] = f2bf(o[nd][1] / l1);
    out[(orow0 + g * 4 + 2) * 1024 + dcol] = f2bf(o[nd][2] / l2);
    out[(orow0 + g * 4 + 3) * 1024 + dcol] = f2bf(o[nd][3] / l3);
  }
}

// ---------------- launcher ----------------
extern "C" void kernel_launch(void* const* d_in, const int* in_sizes, int n_in,
                              void* d_out, int out_size, void* d_ws, size_t ws_size,
                              hipStream_t stream) {
  (void)in_sizes; (void)n_in; (void)out_size; (void)ws_size;
  const float* x     = (const float*)d_in[0];  // [4,2048,1024]
  const float* w_in  = (const float*)d_in[1];  // [1024,3072]
  const float* b_in  = (const float*)d_in[2];  // [3072]
  const float* w_out = (const float*)d_in[3];  // [1024,1024]
  const float* b_out = (const float*)d_in[4];  // [1024]
  float* out = (float*)d_out;                  // [4,2048,1024] fp32

  char* ws = (char*)d_ws;
  u16* Xbf   = (u16*)ws; ws += (size_t)8192 * 1024 * 2;  // 16.8 MB (reused as vT after gemm1)
  u16* WinT  = (u16*)ws; ws += (size_t)3072 * 1024 * 2;  //  6.3 MB
  u16* WoutT = (u16*)ws; ws += (size_t)1024 * 1024 * 2;  //  2.1 MB
  u16* qkv   = (u16*)ws; ws += (size_t)8192 * 3072 * 2;  // 50.3 MB
  u16* attno = (u16*)ws; ws += (size_t)8192 * 1024 * 2;  // 16.8 MB   (total ~92.3 MB)
  u16* vT    = Xbf;  // alias: Xbf dead after gemm1; vT written after gemm1 (stream-ordered)

  cvt_f32_to_bf16<<<2048, 256, 0, stream>>>(x, Xbf, 8192 * 1024 / 4);
  transpose_cvt<<<dim3(16, 48), 256, 0, stream>>>(w_in, WinT, 1024, 3072, 1024, QSCALE);
  transpose_cvt<<<dim3(16, 16), 256, 0, stream>>>(w_out, WoutT, 1024, 1024, 0, 1.0f);
  gemm_bf16<true ><<<dim3(64, 24), 256, 0, stream>>>(Xbf,   WinT,  b_in,  qkv, 8192, 3072, 1024, 1024);
  transpose_v<<<dim3(32, 64), 256, 0, stream>>>(qkv, vT);
  attn_kernel<<<dim3(32, 64), 256, 0, stream>>>(qkv, vT, attno);
  gemm_bf16<false><<<dim3(64, 8),  256, 0, stream>>>(attno, WoutT, b_out, out, 8192, 1024, 1024, 0);
}

// Round 4
// 253.195 us; speedup vs baseline: 1.7472x; 1.0466x over previous
//
#include <hip/hip_runtime.h>
#include <hip/hip_bf16.h>

typedef unsigned short u16;
typedef __attribute__((ext_vector_type(8))) short bf16x8;
typedef __attribute__((ext_vector_type(4))) float f32x4;

#define QSCALE 0.180336880f   // 0.125 * log2(e): softmax computed in exp2 domain

#define DEV static __device__ __forceinline__

DEV u16 f2bf(float f) {
  union { float f; unsigned u; } v; v.f = f;
  unsigned r = v.u + 0x7fffu + ((v.u >> 16) & 1u);  // round-to-nearest-even
  return (u16)(r >> 16);
}

DEV unsigned pk2(float a, float b) {   // two f32 -> packed bf16x2 (RNE)
  union { __hip_bfloat162 h; unsigned u; } c;
  c.h = __float22bfloat162_rn(make_float2(a, b));
  return c.u;
}

DEV void gll16(void* lds, const void* g) {
  __builtin_amdgcn_global_load_lds(
      (const __attribute__((address_space(1))) unsigned int*)g,
      (__attribute__((address_space(3))) unsigned int*)lds, 16, 0, 0);
}

// ---------------- pack: fp32 -> bf16 ----------------
__global__ __launch_bounds__(256) void cvt_f32_to_bf16(const float* __restrict__ in,
                                                       u16* __restrict__ out, int n4) {
  int i = blockIdx.x * blockDim.x + threadIdx.x;
  int stride = gridDim.x * blockDim.x;
  for (; i < n4; i += stride) {
    float4 f = ((const float4*)in)[i];
    ushort4 u;
    u.x = f2bf(f.x); u.y = f2bf(f.y); u.z = f2bf(f.z); u.w = f2bf(f.w);
    ((ushort4*)out)[i] = u;
  }
}

// ---------------- pack: W[K][N] fp32 -> Wt[N][K] bf16, cols < sn scaled ----------------
__global__ __launch_bounds__(256) void transpose_cvt(const float* __restrict__ W,
                                                     u16* __restrict__ Wt,
                                                     int K, int N, int sn, float sval) {
  __shared__ u16 t[64][65];
  const int k0 = blockIdx.x * 64, n0 = blockIdx.y * 64;
  const int tid = threadIdx.x;
  const int rr = tid >> 4;        // 0..15
  const int cc = (tid & 15) * 4;  // 0..60
  const float scl = (n0 < sn) ? sval : 1.0f;   // n0 is 64-aligned, sn is 1024
#pragma unroll
  for (int i = 0; i < 4; ++i) {
    const int row = rr * 4 + i;
    float4 f = *(const float4*)&W[(size_t)(k0 + row) * N + n0 + cc];
    t[row][cc + 0] = f2bf(f.x * scl);
    t[row][cc + 1] = f2bf(f.y * scl);
    t[row][cc + 2] = f2bf(f.z * scl);
    t[row][cc + 3] = f2bf(f.w * scl);
  }
  __syncthreads();
#pragma unroll
  for (int i = 0; i < 4; ++i) {
    const int n = rr * 4 + i;
    ushort4 u;
    u.x = t[cc + 0][n]; u.y = t[cc + 1][n]; u.z = t[cc + 2][n]; u.w = t[cc + 3][n];
    *(ushort4*)&Wt[(size_t)(n0 + n) * K + k0 + cc] = u;
  }
}

// ---------------- transpose V part of qkv: -> vT[bh][d][t] (fallback path) --------
__global__ __launch_bounds__(256) void transpose_v(const u16* __restrict__ qkv,
                                                   u16* __restrict__ vT) {
  __shared__ u16 t[64][72];
  const int bh = blockIdx.y;          // b*16+h
  const int b = bh >> 4, h = bh & 15;
  const int t0 = blockIdx.x * 64;
  const int tid = threadIdx.x;
  const int row = tid >> 2;           // token within tile, 0..63
  const int cg = (tid & 3) * 16;      // d group
  const size_t src = (size_t)b * 2048 * 3072 + (size_t)(t0 + row) * 3072 + 2048 + h * 64 + cg;
  bf16x8 v0 = *(const bf16x8*)&qkv[src];
  bf16x8 v1 = *(const bf16x8*)&qkv[src + 8];
#pragma unroll
  for (int i = 0; i < 8; ++i) { t[row][cg + i] = (u16)v0[i]; t[row][cg + 8 + i] = (u16)v1[i]; }
  __syncthreads();
  const int d = tid >> 2;             // 0..63
  const int tg = (tid & 3) * 16;
  bf16x8 o0, o1;
#pragma unroll
  for (int i = 0; i < 8; ++i) { o0[i] = (short)t[tg + i][d]; o1[i] = (short)t[tg + 8 + i][d]; }
  u16* dst = &vT[((size_t)bh * 64 + d) * 2048 + t0 + tg];
  *(bf16x8*)dst = o0;
  *(bf16x8*)(dst + 8) = o1;
}

// ---------------- bf16 GEMM: C[M][N] = A[M][K] * Bt[N][K]^T + bias ----------------
// 128x128 tile, BK=64, 256 threads (4 waves, 2x2), each wave 64x64 = 4x4 frags.
// Bias for cols < qn scaled by QSCALE. If vTout != null, cols >= vn0 are written
// transposed to vT[bh][d][t] layout instead of Cout (fused V-transpose).
template<bool OUT_BF16>
__global__ __launch_bounds__(256) void gemm_bf16(const u16* __restrict__ A,
                                                 const u16* __restrict__ Bt,
                                                 const float* __restrict__ bias,
                                                 void* __restrict__ Cout,
                                                 int M, int N, int K, int qn,
                                                 u16* __restrict__ vTout, int vn0) {
  __shared__ __align__(16) u16 As[128][64];
  __shared__ __align__(16) u16 Bs[128][64];
  const int tid = threadIdx.x;
  const int wave = tid >> 6, lane = tid & 63;
  const int g = lane >> 4, lr = lane & 15;
  const int bm = blockIdx.x * 128, bn = blockIdx.y * 128;
  const int wm = (wave >> 1) * 64, wn = (wave & 1) * 64;
  f32x4 acc[4][4] = {};
  for (int kt = 0; kt < K; kt += 64) {
    __syncthreads();
#pragma unroll
    for (int j = 0; j < 4; ++j) {
      int chunk = wave * 4 + j;          // 16 chunks of 1KB each per tile
      int e = chunk * 512 + lane * 8;    // element index in 128x64 tile
      int r = e >> 6, c = e & 63;
      gll16((u16*)As + chunk * 512, &A[(size_t)(bm + r) * K + kt + c]);
      gll16((u16*)Bs + chunk * 512, &Bt[(size_t)(bn + r) * K + kt + c]);
    }
    __syncthreads();
#pragma unroll
    for (int kk = 0; kk < 64; kk += 32) {
      bf16x8 af[4], bfr[4];
#pragma unroll
      for (int m = 0; m < 4; ++m)
        af[m] = *(const bf16x8*)&As[wm + m * 16 + lr][kk + g * 8];
#pragma unroll
      for (int n = 0; n < 4; ++n)
        bfr[n] = *(const bf16x8*)&Bs[wn + n * 16 + lr][kk + g * 8];
#pragma unroll
      for (int m = 0; m < 4; ++m)
#pragma unroll
        for (int n = 0; n < 4; ++n)
          acc[m][n] = __builtin_amdgcn_mfma_f32_16x16x32_bf16(af[m], bfr[n], acc[m][n], 0, 0, 0);
    }
  }
#pragma unroll
  for (int m = 0; m < 4; ++m) {
#pragma unroll
    for (int n = 0; n < 4; ++n) {
      const int col = bn + wn + n * 16 + lr;
      float bv = bias ? bias[col] : 0.f;
      if (col < qn) bv *= QSCALE;
      if (vTout != nullptr && col >= vn0) {
        const int hc = col - vn0;   // h*64 + d
#pragma unroll
        for (int r = 0; r < 4; ++r) {
          const int row = bm + wm + m * 16 + g * 4 + r;   // b*2048 + t
          const size_t idx = (((size_t)(row >> 11) * 16 + (hc >> 6)) * 64 + (hc & 63)) * 2048
                             + (row & 2047);
          vTout[idx] = f2bf(acc[m][n][r] + bv);
        }
      } else {
#pragma unroll
        for (int r = 0; r < 4; ++r) {
          const int row = bm + wm + m * 16 + g * 4 + r;   // C/D: col=lane&15, row=(lane>>4)*4+reg
          float v = acc[m][n][r] + bv;
          if (OUT_BF16) ((u16*)Cout)[(size_t)row * N + col] = f2bf(v);
          else          ((float*)Cout)[(size_t)row * N + col] = v;
        }
      }
    }
  }
}

// ---------------- flash attention: swapped QK^T, in-reg softmax, hoisted addressing --
// grid (S/64, B*H); block 256 = 4 waves; wave w owns q rows [q0+16w, q0+16w+16).
// qkv: [B*S][3072] bf16 (Q pre-scaled by QSCALE); vT: [bh][d][t].
// Swapped QK: s[n] = mfma(kf, qf) -> s[n][r] = S[key=n*16+g*4+r][q=lr].
// All LDS offsets loop-invariant (precomputed); tile loop unrolled x2 so the
// double-buffer index is compile-time; stage sources advance incrementally.

#define ATTN_BODY(BUF, PRE)                                                     \
  {                                                                             \
    if (PRE) {                                                                  \
      gll16((u16*)Ks[(BUF) ^ 1] + c0 * 512, gk0); gk0 += 64 * 3072;             \
      gll16((u16*)Ks[(BUF) ^ 1] + c1 * 512, gk1); gk1 += 64 * 3072;             \
      gll16((u16*)Vs[(BUF) ^ 1] + c0 * 512, gv0); gv0 += 64;                    \
      gll16((u16*)Vs[(BUF) ^ 1] + c1 * 512, gv1); gv1 += 64;                    \
    }                                                                           \
    const char* kb = (const char*)Ks[(BUF)];                                    \
    const char* vb = (const char*)Vs[(BUF)];                                    \
    f32x4 s[4] = {};                                                            \
    _Pragma("unroll")                                                           \
    for (int kk = 0; kk < 2; ++kk)                                              \
      _Pragma("unroll")                                                         \
      for (int n = 0; n < 4; ++n) {                                             \
        bf16x8 kf = *(const bf16x8*)(kb + off[kk][n]);                          \
        s[n] = __builtin_amdgcn_mfma_f32_16x16x32_bf16(kf, qf[kk], s[n], 0, 0, 0); \
      }                                                                         \
    f32x4 t01, t23;                                                             \
    _Pragma("unroll")                                                           \
    for (int i = 0; i < 4; ++i) {                                               \
      t01[i] = fmaxf(s[0][i], s[1][i]);                                         \
      t23[i] = fmaxf(s[2][i], s[3][i]);                                         \
    }                                                                           \
    float pmax = fmaxf(fmaxf(fmaxf(t01[0], t23[0]), fmaxf(t01[1], t23[1])),     \
                       fmaxf(fmaxf(t01[2], t23[2]), fmaxf(t01[3], t23[3])));    \
    if (!__all(pmax <= m + 8.f)) {                                              \
      float pm = fmaxf(pmax, __shfl_xor(pmax, 16));                             \
      pm = fmaxf(pm, __shfl_xor(pm, 32));                                       \
      float mnew = fmaxf(m, pm);                                                \
      float sc = __builtin_amdgcn_exp2f(m - mnew);                              \
      float sc0 = __shfl(sc, g * 4 + 0);                                        \
      float sc1 = __shfl(sc, g * 4 + 1);                                        \
      float sc2 = __shfl(sc, g * 4 + 2);                                        \
      float sc3 = __shfl(sc, g * 4 + 3);                                        \
      _Pragma("unroll")                                                         \
      for (int nd = 0; nd < 4; ++nd) {                                          \
        o[nd][0] *= sc0; o[nd][1] *= sc1; o[nd][2] *= sc2; o[nd][3] *= sc3;     \
      }                                                                         \
      lsum *= sc;                                                               \
      m = mnew;                                                                 \
    }                                                                           \
    float su = 0.f;                                                             \
    _Pragma("unroll")                                                           \
    for (int n = 0; n < 4; ++n) {                                               \
      float p0 = __builtin_amdgcn_exp2f(s[n][0] - m);                           \
      float p1 = __builtin_amdgcn_exp2f(s[n][1] - m);                           \
      float p2 = __builtin_amdgcn_exp2f(s[n][2] - m);                           \
      float p3 = __builtin_amdgcn_exp2f(s[n][3] - m);                           \
      uint2 w;                                                                  \
      w.x = pk2(p0, p1);                                                        \
      w.y = pk2(p2, p3);                                                        \
      *(uint2*)(pb + pwo[n]) = w;                                               \
      su += (p0 + p1) + (p2 + p3);                                              \
    }                                                                           \
    lsum += su;                                                                 \
    _Pragma("unroll")                                                           \
    for (int kk = 0; kk < 2; ++kk) {                                            \
      bf16x8 pf = *(const bf16x8*)(pb + off[kk][0]);                            \
      _Pragma("unroll")                                                         \
      for (int nd = 0; nd < 4; ++nd) {                                          \
        bf16x8 vf = *(const bf16x8*)(vb + off[kk][nd]);                         \
        o[nd] = __builtin_amdgcn_mfma_f32_16x16x32_bf16(pf, vf, o[nd], 0, 0, 0); \
      }                                                                         \
    }                                                                           \
    __syncthreads();                                                            \
  }

__global__ __launch_bounds__(256) void attn_kernel(const u16* __restrict__ qkv,
                                                   const u16* __restrict__ vT,
                                                   u16* __restrict__ out) {
  __shared__ __align__(16) u16 Ks[2][4096];   // K tile [key][d], swizzled
  __shared__ __align__(16) u16 Vs[2][4096];   // V^T tile [d][key], swizzled
  __shared__ __align__(16) u16 Ps[4][1024];   // per-wave P [qrow][key], swizzled
  const int tid = threadIdx.x;
  const int wave = tid >> 6, lane = tid & 63;
  const int g = lane >> 4, lr = lane & 15;
  const int bh = blockIdx.y;
  const int b = bh >> 4, h = bh & 15;
  const int q0 = blockIdx.x * 64;
  const size_t base = (size_t)b * 2048 * 3072;
  const u16* kg = qkv + base + 1024 + h * 64;        // + t*3072 + d
  const u16* vg = vT + (size_t)bh * 64 * 2048;       // + d*2048 + t

  const int qrow = q0 + wave * 16 + lr;
  bf16x8 qf[2];
#pragma unroll
  for (int kk = 0; kk < 2; ++kk)
    qf[kk] = *(const bf16x8*)&qkv[base + (size_t)qrow * 3072 + h * 64 + kk * 32 + g * 8];

  // loop-invariant swizzled LDS byte offsets (shared by K-reads, V-reads, P-reads)
  const int sw = (lr & 7) << 4;
  int off[2][4];
#pragma unroll
  for (int kk = 0; kk < 2; ++kk)
#pragma unroll
    for (int n = 0; n < 4; ++n)
      off[kk][n] = (n * 16 + lr) * 128 + ((kk * 64 + g * 16) ^ sw);
  int pwo[4];
#pragma unroll
  for (int n = 0; n < 4; ++n)
    pwo[n] = lr * 128 + ((n * 32 + g * 8) ^ sw);
  char* const pb = (char*)Ps[wave];

  // per-lane incremental stage source pointers (r/cb decode done once)
  const int c0 = wave * 2, c1 = c0 + 1;
  const int a0 = c0 * 1024 + lane * 16, a1 = c1 * 1024 + lane * 16;
  const int r0 = a0 >> 7, r1 = a1 >> 7;
  const int cb0 = (a0 & 127) ^ ((r0 & 7) << 4), cb1 = (a1 & 127) ^ ((r1 & 7) << 4);
  const u16* gk0 = kg + (size_t)r0 * 3072 + (cb0 >> 1);
  const u16* gk1 = kg + (size_t)r1 * 3072 + (cb1 >> 1);
  const u16* gv0 = vg + (size_t)r0 * 2048 + (cb0 >> 1);
  const u16* gv1 = vg + (size_t)r1 * 2048 + (cb1 >> 1);

  f32x4 o[4] = {};
  float m = -1e30f, lsum = 0.f;

  // prologue: stage tile 0 into buf 0
  gll16((u16*)Ks[0] + c0 * 512, gk0); gk0 += 64 * 3072;
  gll16((u16*)Ks[0] + c1 * 512, gk1); gk1 += 64 * 3072;
  gll16((u16*)Vs[0] + c0 * 512, gv0); gv0 += 64;
  gll16((u16*)Vs[0] + c1 * 512, gv1); gv1 += 64;
  __syncthreads();

  for (int it2 = 0; it2 < 16; ++it2) {
    ATTN_BODY(0, 1)
    ATTN_BODY(1, it2 < 15)
  }

  // final row-sum reduce + redistribute to o's rows (g*4+r)
  float lf = lsum + __shfl_xor(lsum, 16);
  lf += __shfl_xor(lf, 32);
  float l0 = __shfl(lf, g * 4 + 0);
  float l1 = __shfl(lf, g * 4 + 1);
  float l2 = __shfl(lf, g * 4 + 2);
  float l3 = __shfl(lf, g * 4 + 3);
  const size_t orow0 = (size_t)b * 2048 + q0 + wave * 16;
#pragma unroll
  for (int nd = 0; nd < 4; ++nd) {
    const int dcol = h * 64 + nd * 16 + lr;
    out[(orow0 + g * 4 + 0) * 1024 + dcol] = f2bf(o[nd][0] / l0);
    out[(orow0 + g * 4 + 1) * 1024 + dcol] = f2bf(o[nd][1] / l1);
    out[(orow0 + g * 4 + 2) * 1024 + dcol] = f2bf(o[nd][2] / l2);
    out[(orow0 + g * 4 + 3) * 1024 + dcol] = f2bf(o[nd][3] / l3);
  }
}

// ---------------- launcher ----------------
extern "C" void kernel_launch(void* const* d_in, const int* in_sizes, int n_in,
                              void* d_out, int out_size, void* d_ws, size_t ws_size,
                              hipStream_t stream) {
  (void)in_sizes; (void)n_in; (void)out_size;
  const float* x     = (const float*)d_in[0];  // [4,2048,1024]
  const float* w_in  = (const float*)d_in[1];  // [1024,3072]
  const float* b_in  = (const float*)d_in[2];  // [3072]
  const float* w_out = (const float*)d_in[3];  // [1024,1024]
  const float* b_out = (const float*)d_in[4];  // [1024]
  float* out = (float*)d_out;                  // [4,2048,1024] fp32

  char* ws = (char*)d_ws;
  u16* Xbf   = (u16*)ws; ws += (size_t)8192 * 1024 * 2;  // 16.8 MB
  u16* WinT  = (u16*)ws; ws += (size_t)3072 * 1024 * 2;  //  6.3 MB
  u16* WoutT = (u16*)ws; ws += (size_t)1024 * 1024 * 2;  //  2.1 MB
  u16* qkv   = (u16*)ws; ws += (size_t)8192 * 3072 * 2;  // 50.3 MB
  u16* attno = (u16*)ws; ws += (size_t)8192 * 1024 * 2;  // 16.8 MB  (base total ~92.3 MB)
  u16* vTsep = (u16*)ws;                                  // +16.8 MB if it fits

  const size_t fused_need = 92274688ull + 16777216ull;   // 109 MB
  const bool fused = (ws_size >= fused_need);
  u16* vT = fused ? vTsep : Xbf;   // fallback: alias Xbf (dead after gemm1)

  cvt_f32_to_bf16<<<2048, 256, 0, stream>>>(x, Xbf, 8192 * 1024 / 4);
  transpose_cvt<<<dim3(16, 48), 256, 0, stream>>>(w_in, WinT, 1024, 3072, 1024, QSCALE);
  transpose_cvt<<<dim3(16, 16), 256, 0, stream>>>(w_out, WoutT, 1024, 1024, 0, 1.0f);
  if (fused) {
    // V columns written directly in vT[bh][d][t] layout by the GEMM epilogue
    gemm_bf16<true ><<<dim3(64, 24), 256, 0, stream>>>(Xbf, WinT, b_in, qkv,
                                                       8192, 3072, 1024, 1024, vT, 2048);
  } else {
    gemm_bf16<true ><<<dim3(64, 24), 256, 0, stream>>>(Xbf, WinT, b_in, qkv,
                                                       8192, 3072, 1024, 1024, nullptr, 1 << 30);
    transpose_v<<<dim3(32, 64), 256, 0, stream>>>(qkv, vT);
  }
  attn_kernel<<<dim3(32, 64), 256, 0, stream>>>(qkv, vT, attno);
  gemm_bf16<false><<<dim3(64, 8), 256, 0, stream>>>(attno, WoutT, b_out, out,
                                                    8192, 1024, 1024, 0, nullptr, 1 << 30);
}